// Round 2
// baseline (276.229 us; speedup 1.0000x reference)
//
#include <hip/hip_runtime.h>
#include <stdint.h>

#define C_DIM 8192
#define O_DIM 8192
#define M_DIM 256
#define NG    128     // C/64 groups
#define RK    32

typedef float f32x4 __attribute__((ext_vector_type(4)));
typedef short s16x8 __attribute__((ext_vector_type(8)));
typedef int   i32x4 __attribute__((ext_vector_type(4)));
typedef unsigned int u32;

union FragU { uint4 u; s16x8 s; };

// ---------------------------------------------------------------------------
// k_lora: lact[m][r] = sum_k x[m][k] * pd[k][r]   (256 x 32, f32)
// grid 128 blocks * 256 threads; block = 2 m-rows; thread = (ml, rq, kc)
// ---------------------------------------------------------------------------
__global__ __launch_bounds__(256) void k_lora(const float* __restrict__ x,
                                              const float* __restrict__ pd,
                                              float* __restrict__ lact) {
  const int t  = threadIdx.x;
  const int ml = t >> 7;          // 0..1
  const int rq = (t >> 4) & 7;    // 0..7 (r-quad)
  const int kc = t & 15;          // 0..15 (k-chunk of 512)
  const int m  = blockIdx.x * 2 + ml;
  const float* xrow = x + (size_t)m * C_DIM + kc * 512;
  const float* pdp  = pd + (size_t)(kc * 512) * RK + rq * 4;
  float a0 = 0.f, a1 = 0.f, a2 = 0.f, a3 = 0.f;
  for (int k = 0; k < 512; k += 4) {
    float4 xv = *(const float4*)(xrow + k);
    float4 p0 = *(const float4*)(pdp + (size_t)(k + 0) * RK);
    float4 p1 = *(const float4*)(pdp + (size_t)(k + 1) * RK);
    float4 p2 = *(const float4*)(pdp + (size_t)(k + 2) * RK);
    float4 p3 = *(const float4*)(pdp + (size_t)(k + 3) * RK);
    a0 += xv.x * p0.x + xv.y * p1.x + xv.z * p2.x + xv.w * p3.x;
    a1 += xv.x * p0.y + xv.y * p1.y + xv.z * p2.y + xv.w * p3.y;
    a2 += xv.x * p0.z + xv.y * p1.z + xv.z * p2.z + xv.w * p3.z;
    a3 += xv.x * p0.w + xv.y * p1.w + xv.z * p2.w + xv.w * p3.w;
  }
  __shared__ float red[2][8][16][4];
  red[ml][rq][kc][0] = a0;
  red[ml][rq][kc][1] = a1;
  red[ml][rq][kc][2] = a2;
  red[ml][rq][kc][3] = a3;
  __syncthreads();
  if (t < 64) {
    const int ml2 = t >> 5, r = t & 31, rq2 = r >> 2, j = r & 3;
    float s = 0.f;
#pragma unroll
    for (int c = 0; c < 16; ++c) s += red[ml2][rq2][c][j];
    lact[(size_t)(blockIdx.x * 2 + ml2) * RK + r] = s;
  }
}

// ---------------------------------------------------------------------------
// k_prep: smooth + per-group int4 quantize of activations.
// Writes asc[g][m] (f32) and q_act as bf16 MFMA A-fragments:
//   wsA[((MT*128+g)*2+f)*64 + lane] = 8 bf16: A[lane&15][f*32+(lane>>4)*8+j]
// grid = 16 MT * 8 gblk = 128 blocks * 256 threads; thread=(gl,ml)
// ---------------------------------------------------------------------------
__global__ __launch_bounds__(256) void k_prep(const float* __restrict__ x,
                                              const float* __restrict__ smooth,
                                              float* __restrict__ asc,
                                              uint4* __restrict__ wsA) {
  const int t    = threadIdx.x;
  const int ml   = t & 15;
  const int gl   = t >> 4;
  const int MT   = blockIdx.x >> 3;
  const int gblk = blockIdx.x & 7;
  const int m = MT * 16 + ml;
  const int g = gblk * 16 + gl;
  const float* xp = x + (size_t)m * C_DIM + g * 64;
  const float* sp = smooth + g * 64;
  float xs[64];
  float amax = 0.0f;
#pragma unroll
  for (int i = 0; i < 64; i += 4) {
    float4 xv = *(const float4*)(xp + i);
    float4 sv = *(const float4*)(sp + i);
    xs[i + 0] = xv.x / sv.x;
    xs[i + 1] = xv.y / sv.y;
    xs[i + 2] = xv.z / sv.z;
    xs[i + 3] = xv.w / sv.w;
    amax = fmaxf(amax, fabsf(xs[i + 0]));
    amax = fmaxf(amax, fabsf(xs[i + 1]));
    amax = fmaxf(amax, fabsf(xs[i + 2]));
    amax = fmaxf(amax, fabsf(xs[i + 3]));
  }
  const float ascale = fmaxf(amax / 7.0f, 1e-8f);   // match reference exactly
  asc[g * M_DIM + m] = ascale;
  const size_t base = ((size_t)(MT * NG + g)) * 2 * 64;
#pragma unroll
  for (int f = 0; f < 2; ++f) {
#pragma unroll
    for (int s2 = 0; s2 < 4; ++s2) {
      const int i0 = f * 32 + s2 * 8;
      u32 b[8];
#pragma unroll
      for (int e = 0; e < 8; ++e) {
        float qv = fminf(fmaxf(rintf(xs[i0 + e] / ascale), -8.0f), 7.0f);
        b[e] = __float_as_uint(qv) >> 16;   // exact bf16 for small ints
      }
      uint4 c;
      c.x = b[0] | (b[1] << 16);
      c.y = b[2] | (b[3] << 16);
      c.z = b[4] | (b[5] << 16);
      c.w = b[6] | (b[7] << 16);
      wsA[base + (size_t)f * 64 + s2 * 16 + ml] = c;
    }
  }
}

// ---------------------------------------------------------------------------
// k_main: out[m][n] = sum_g ascale[m][g]*wscale[g][n]*(q_a . q_w)
//                   + bias[n] + lact[m] . pu[n]
// grid 256 blocks (32 n-cols each, all 256 m) * 512 threads (8 waves).
// wave w: rows [w*32, w*32+32) (m-tiles MT0, MT0+1) x both n-tiles.
// qweight: read once, coalesced, nontemporal, depth-2 prefetch, bf16 in
// double-buffered LDS. One raw s_barrier per group (vmcnt NOT drained).
// Pipeline invariant entering iter g: cA = codes(g+1), cB = codes(g+2).
// ---------------------------------------------------------------------------
__global__ __launch_bounds__(512, 2) void k_main(
    const int* __restrict__ qw, const float* __restrict__ wsc,
    const float* __restrict__ pu, const float* __restrict__ bias,
    const float* __restrict__ asc, const uint4* __restrict__ wsA,
    const float* __restrict__ lact, float* __restrict__ out) {
  const int t    = threadIdx.x;
  const int n0   = blockIdx.x * 32;
  const int w    = t >> 6;
  const int l    = t & 63;
  const int lrow = l >> 4;    // 0..3
  const int lcol = l & 15;

  __shared__ uint4 ldsB[2][2][2][64];   // [buf][f][nt][lane], 8KB

  // staging mapping: thread -> (n, 4 consecutive k) -> one uint2 frag slot
  const int sn    = t >> 4;            // 0..31 (n within block)
  const int kk    = (t & 15) * 4;      // 0..60 (k within group)
  const int sf    = kk >> 5;           // frag (K=32 half)
  const int ss    = (kk & 31) >> 3;    // lane-hi slot
  const int shalf = (kk & 7) >> 2;     // which uint2 half
  const int snt   = sn >> 4;
  const int scol  = sn & 15;
  const int* qrow = qw + (size_t)(n0 + sn) * C_DIM + kk;
  uint2* stgt = (uint2*)&ldsB[0][sf][snt][scol + 16 * ss] + shalf;

  const int MT0 = w * 2;

  f32x4 acc[2][2];
#pragma unroll
  for (int a = 0; a < 2; ++a)
#pragma unroll
    for (int bb = 0; bb < 2; ++bb) acc[a][bb] = (f32x4){0.f, 0.f, 0.f, 0.f};

  uint4 aC[2][2], aN[2][2];
  f32x4 asC[2], asN[2];
  float wsC[2], wsN[2];
  i32x4 cA, cB;

  auto LOADA = [&](int g, uint4 (&a)[2][2]) {
#pragma unroll
    for (int mt = 0; mt < 2; ++mt)
#pragma unroll
      for (int f = 0; f < 2; ++f)
        a[mt][f] = wsA[(((size_t)(MT0 + mt) * NG + g) * 2 + f) * 64 + l];
  };
  auto LOADS = [&](int g, f32x4 (&as)[2], float (&ws)[2]) {
#pragma unroll
    for (int mt = 0; mt < 2; ++mt)
      as[mt] = *(const f32x4*)(asc + (size_t)g * M_DIM + (MT0 + mt) * 16 + lrow * 4);
#pragma unroll
    for (int nt = 0; nt < 2; ++nt)
      ws[nt] = wsc[(size_t)g * O_DIM + n0 + nt * 16 + lcol];
  };
  auto STAGELOAD = [&](int g) -> i32x4 {
    return __builtin_nontemporal_load((const i32x4*)(qrow + (size_t)g * 64));
  };
  auto STAGEWRITE = [&](int buf, i32x4 c) {
    u32 b0 = __float_as_uint((float)(c[0] - 8)) >> 16;
    u32 b1 = __float_as_uint((float)(c[1] - 8)) >> 16;
    u32 b2 = __float_as_uint((float)(c[2] - 8)) >> 16;
    u32 b3 = __float_as_uint((float)(c[3] - 8)) >> 16;
    uint2 d;
    d.x = b0 | (b1 << 16);
    d.y = b2 | (b3 << 16);
    stgt[(size_t)buf * 512] = d;   // 512 uint2 = 4KB = one buffer
  };

  // prologue: fill buf0 with g=0; prefetch codes g=1,2; A/S for g=0
  {
    i32x4 cP = STAGELOAD(0);
    LOADA(0, aC);
    LOADS(0, asC, wsC);
    cA = STAGELOAD(1);
    STAGEWRITE(0, cP);
    cB = STAGELOAD(2);
  }

  for (int g = 0; g < NG; ++g) {
    // publish this wave's ds_writes, then sync; vmcnt NOT drained.
    asm volatile("s_waitcnt lgkmcnt(0)\n\ts_barrier" ::: "memory");
    const int buf = g & 1;
    FragU bf[2][2];
#pragma unroll
    for (int f = 0; f < 2; ++f)
#pragma unroll
      for (int nt = 0; nt < 2; ++nt) bf[f][nt].u = ldsB[buf][f][nt][l];

    if (g < NG - 1) {
      LOADA(g + 1, aN);
      LOADS(g + 1, asN, wsN);
    }

#pragma unroll
    for (int mt = 0; mt < 2; ++mt) {
      FragU a0, a1;
      a0.u = aC[mt][0];
      a1.u = aC[mt][1];
#pragma unroll
      for (int nt = 0; nt < 2; ++nt) {
        f32x4 d = (f32x4){0.f, 0.f, 0.f, 0.f};
        d = __builtin_amdgcn_mfma_f32_16x16x32_bf16(a0.s, bf[0][nt].s, d, 0, 0, 0);
        d = __builtin_amdgcn_mfma_f32_16x16x32_bf16(a1.s, bf[1][nt].s, d, 0, 0, 0);
        acc[mt][nt] += d * (asC[mt] * wsC[nt]);   // exact int dot * group scale
      }
    }

    if (g < NG - 1) {
      STAGEWRITE(buf ^ 1, cA);
      cA = cB;
      if (g < NG - 3) cB = STAGELOAD(g + 3);   // FIX: was g+2 (stale-tile bug)
#pragma unroll
      for (int mt = 0; mt < 2; ++mt) {
#pragma unroll
        for (int f = 0; f < 2; ++f) aC[mt][f] = aN[mt][f];
        asC[mt] = asN[mt];
        wsC[mt] = wsN[mt];
      }
    }
  }

  // epilogue: + bias + lora
#pragma unroll
  for (int nt = 0; nt < 2; ++nt) {
    const int n = n0 + nt * 16 + lcol;
    const float bv = bias[n];
    float4 puq[8];
#pragma unroll
    for (int rq = 0; rq < 8; ++rq)
      puq[rq] = *(const float4*)(pu + (size_t)n * RK + rq * 4);
#pragma unroll
    for (int mt = 0; mt < 2; ++mt) {
#pragma unroll
      for (int j = 0; j < 4; ++j) {
        const int m = (MT0 + mt) * 16 + lrow * 4 + j;
        const float* lp = lact + (size_t)m * RK;
        float lo = 0.f;
#pragma unroll
        for (int rq = 0; rq < 8; ++rq) {
          float4 lv = *(const float4*)(lp + rq * 4);
          lo += lv.x * puq[rq].x + lv.y * puq[rq].y + lv.z * puq[rq].z +
                lv.w * puq[rq].w;
        }
        out[(size_t)m * O_DIM + n] = acc[mt][nt][j] + bv + lo;
      }
    }
  }
}

// ---------------------------------------------------------------------------
extern "C" void kernel_launch(void* const* d_in, const int* in_sizes, int n_in,
                              void* d_out, int out_size, void* d_ws,
                              size_t ws_size, hipStream_t stream) {
  const float* x      = (const float*)d_in[0];
  const int*   qw     = (const int*)d_in[1];
  const float* wsc    = (const float*)d_in[2];
  const float* smooth = (const float*)d_in[3];
  const float* pd     = (const float*)d_in[4];
  const float* pu     = (const float*)d_in[5];
  const float* bias   = (const float*)d_in[6];
  float* out = (float*)d_out;

  char* ws = (char*)d_ws;
  float* lact = (float*)ws;                    // 256*32*4   = 32 KB
  float* asc  = (float*)(ws + 32 * 1024);      // 128*256*4  = 128 KB
  uint4* wsA  = (uint4*)(ws + 160 * 1024);     // 4 MB bf16 A-fragments

  hipLaunchKernelGGL(k_lora, dim3(128), dim3(256), 0, stream, x, pd, lact);
  hipLaunchKernelGGL(k_prep, dim3(128), dim3(256), 0, stream, x, smooth, asc, wsA);
  hipLaunchKernelGGL(k_main, dim3(256), dim3(512), 0, stream, qw, wsc, pu, bias,
                     asc, wsA, lact, out);
}